// Round 1
// baseline (322.413 us; speedup 1.0000x reference)
//
#include <hip/hip_runtime.h>

#define K_CODES 1024
#define D_DIM 256
#define HW 1024
#define N_VEC 32768          // 32 * 32 * 32
#define OUT_ELEMS 8388608    // 32 * 256 * 32 * 32

// ws layout:
// [0,     4096)  counts  int[1024]   (zeroed per launch)
// [4096,  4100)  loss accumulator float (zeroed per launch)
// [8192, 12288)  sq_c    float[1024]
// [16384,147456) idx     int[32768]

__global__ __launch_bounds__(256) void sqnorm_kernel(const float* __restrict__ cb,
                                                     float* __restrict__ sq) {
    const int wave = threadIdx.x >> 6;
    const int lane = threadIdx.x & 63;
    const int k = blockIdx.x * 4 + wave;
    const float* row = cb + (size_t)k * D_DIM;
    float s = 0.f;
#pragma unroll
    for (int m = 0; m < 4; ++m) { float v = row[lane + 64 * m]; s += v * v; }
#pragma unroll
    for (int off = 32; off > 0; off >>= 1) s += __shfl_down(s, off, 64);
    if (lane == 0) sq[k] = s;
}

// 512 blocks, 64 n's per block; 256 threads: tx = n-group (8x8n), ty = k-group (32x8k)
__global__ __launch_bounds__(256, 2) void argmin_kernel(
    const float* __restrict__ x, const float* __restrict__ cb,
    const float* __restrict__ sq, int* __restrict__ idx_out,
    int* __restrict__ counts, float* __restrict__ loss_accum) {
    __shared__ float Xs[16][64];
    __shared__ float Cs[16][260];   // padded: 2-way-max bank pattern, 16B-aligned rows
    __shared__ float xsqp[16][64];

    const int t  = threadIdx.x;
    const int tx = t & 7;
    const int ty = t >> 3;
    const int n0 = blockIdx.x * 64;
    const int b  = n0 >> 10;
    const int hw0 = n0 & 1023;
    const float* xbase = x + (size_t)b * D_DIM * HW + hw0;

    // staging maps
    const int sx_d  = t >> 4;         // 0..15
    const int sx_n4 = (t & 15) * 4;   // 0..60
    const int sc_d4 = (t & 3) * 4;    // 0,4,8,12
    const int sc_k  = t >> 2;         // 0..63

    float bestv[8];
    int   bestk[8];
#pragma unroll
    for (int i = 0; i < 8; ++i) { bestv[i] = 3.4e38f; bestk[i] = 0; }
    float xsq4[4] = {0.f, 0.f, 0.f, 0.f};

    for (int kt = 0; kt < 4; ++kt) {
        const int k0 = kt * 256;
        float acc[8][8];
#pragma unroll
        for (int i = 0; i < 8; ++i)
#pragma unroll
            for (int j = 0; j < 8; ++j) acc[i][j] = 0.f;

        for (int dc = 0; dc < 16; ++dc) {
            __syncthreads();
            // stage X chunk [16 d][64 n], coalesced float4 in n
            {
                const float4 xv = *(const float4*)(xbase + (size_t)(dc * 16 + sx_d) * HW + sx_n4);
                *(float4*)&Xs[sx_d][sx_n4] = xv;
                if (kt == 0) {
                    xsq4[0] += xv.x * xv.x; xsq4[1] += xv.y * xv.y;
                    xsq4[2] += xv.z * xv.z; xsq4[3] += xv.w * xv.w;
                }
            }
            // stage C chunk [16 d][256 k]: float4 along d, transpose into LDS
#pragma unroll
            for (int i = 0; i < 4; ++i) {
                const int k = sc_k + 64 * i;
                const float4 cv = *(const float4*)(cb + (size_t)(k0 + k) * D_DIM + dc * 16 + sc_d4);
                Cs[sc_d4 + 0][k] = cv.x; Cs[sc_d4 + 1][k] = cv.y;
                Cs[sc_d4 + 2][k] = cv.z; Cs[sc_d4 + 3][k] = cv.w;
            }
            __syncthreads();
#pragma unroll
            for (int d = 0; d < 16; ++d) {
                float xr[8], cr[8];
                *(float4*)&xr[0] = *(const float4*)&Xs[d][tx * 8];
                *(float4*)&xr[4] = *(const float4*)&Xs[d][tx * 8 + 4];
                *(float4*)&cr[0] = *(const float4*)&Cs[d][ty * 8];
                *(float4*)&cr[4] = *(const float4*)&Cs[d][ty * 8 + 4];
#pragma unroll
                for (int i = 0; i < 8; ++i)
#pragma unroll
                    for (int j = 0; j < 8; ++j)
                        acc[i][j] = fmaf(xr[i], cr[j], acc[i][j]);
            }
        }
        // epilogue: score = ||c||^2 - 2 x.c   (||x||^2 omitted: argmin-invariant)
#pragma unroll
        for (int j = 0; j < 8; ++j) {
            const int k = k0 + ty * 8 + j;
            const float s = sq[k];
#pragma unroll
            for (int i = 0; i < 8; ++i) {
                const float dist = fmaf(-2.f, acc[i][j], s);
                if (dist < bestv[i]) { bestv[i] = dist; bestk[i] = k; }  // k strictly ascending -> first-min kept
            }
        }
    }

    // cross-thread reduction: alias red arrays onto Cs (16640 B >= 16384 B needed)
    float* redv = &Cs[0][0];
    int*   redk = (int*)(&Cs[0][0]) + 2048;
    __syncthreads();
#pragma unroll
    for (int i = 0; i < 8; ++i) {
        redv[(tx * 8 + i) * 32 + ty] = bestv[i];
        redk[(tx * 8 + i) * 32 + ty] = bestk[i];
    }
#pragma unroll
    for (int j = 0; j < 4; ++j) xsqp[sx_d][sx_n4 + j] = xsq4[j];
    __syncthreads();

    if (t < 64) {
        float bv = redv[t * 32];
        int   bk = redk[t * 32];
        for (int j = 1; j < 32; ++j) {
            const float v = redv[t * 32 + j];
            const int  kk = redk[t * 32 + j];
            if (v < bv || (v == bv && kk < bk)) { bv = v; bk = kk; }
        }
        float xs = 0.f;
#pragma unroll
        for (int p = 0; p < 16; ++p) xs += xsqp[p][t];
        idx_out[n0 + t] = bk;
        atomicAdd(&counts[bk], 1);
        float lp = xs + bv;   // ||x - c||^2 for this n
#pragma unroll
        for (int off = 32; off > 0; off >>= 1) lp += __shfl_down(lp, off, 64);
        if (t == 0) atomicAdd(loss_accum, lp);
    }
}

__global__ __launch_bounds__(256) void scatter_kernel(
    const float* __restrict__ x, const float* __restrict__ cb,
    const int* __restrict__ idx, float* __restrict__ out) {
    const int g = (blockIdx.x * 256 + threadIdx.x) * 4;
    const int b  = g >> 18;
    const int c  = (g >> 10) & 255;
    const int hw = g & 1023;
    const int n  = (b << 10) + hw;
    const int4  id4 = *(const int4*)(idx + n);
    const float4 xv = *(const float4*)(x + g);
    float4 o;
    o.x = xv.x + (cb[(size_t)id4.x * D_DIM + c] - xv.x);   // replicate ST fp ordering
    o.y = xv.y + (cb[(size_t)id4.y * D_DIM + c] - xv.y);
    o.z = xv.z + (cb[(size_t)id4.z * D_DIM + c] - xv.z);
    o.w = xv.w + (cb[(size_t)id4.w * D_DIM + c] - xv.w);
    *(float4*)(out + g) = o;
}

__global__ __launch_bounds__(256) void finalize_kernel(
    const int* __restrict__ counts, const float* __restrict__ loss_accum,
    float* __restrict__ out) {
    __shared__ float wsum[4];
    const int t = threadIdx.x;
    float s = 0.f;
#pragma unroll
    for (int m = 0; m < 4; ++m) {
        const float p = (float)counts[t + 256 * m] * (1.f / 32768.f);
        s += p * logf(p + 1e-10f);
    }
#pragma unroll
    for (int off = 32; off > 0; off >>= 1) s += __shfl_down(s, off, 64);
    if ((t & 63) == 0) wsum[t >> 6] = s;
    __syncthreads();
    if (t == 0) {
        const float total = wsum[0] + wsum[1] + wsum[2] + wsum[3];
        out[OUT_ELEMS]     = loss_accum[0] * (1.25f / 8388608.f);  // (1+0.25)*mean
        out[OUT_ELEMS + 1] = expf(-total);
    }
}

extern "C" void kernel_launch(void* const* d_in, const int* in_sizes, int n_in,
                              void* d_out, int out_size, void* d_ws, size_t ws_size,
                              hipStream_t stream) {
    const float* x  = (const float*)d_in[0];
    const float* cb = (const float*)d_in[1];
    float* out = (float*)d_out;
    char* wsb = (char*)d_ws;
    int*   counts = (int*)wsb;
    float* loss   = (float*)(wsb + 4096);
    float* sq     = (float*)(wsb + 8192);
    int*   idx    = (int*)(wsb + 16384);

    hipMemsetAsync(d_ws, 0, 8192, stream);
    sqnorm_kernel<<<256, 256, 0, stream>>>(cb, sq);
    argmin_kernel<<<512, 256, 0, stream>>>(x, cb, sq, idx, counts, loss);
    scatter_kernel<<<8192, 256, 0, stream>>>(x, cb, idx, out);
    finalize_kernel<<<1, 256, 0, stream>>>(counts, loss, out);
}

// Round 2
// 155.400 us; speedup vs baseline: 2.0747x; 2.0747x over previous
//
#include <hip/hip_runtime.h>
#include <hip/hip_bf16.h>

typedef __attribute__((ext_vector_type(8))) short short8;
typedef __attribute__((ext_vector_type(4))) float f32x4;

#define K_CODES 1024
#define D_DIM 256
#define N_VEC 32768
#define OUT_ELEMS 8388608

// ws layout (bytes):
// 0       counts int[1024]          (zeroed)
// 4096    loss   float              (zeroed)
// 8192    sq     float[1024]
// 16384   chi    ushort[1024*256]   (bf16 hi)
// 540672  clo    ushort[1024*256]   (bf16 lo)
// 1064960 partv  float[2*32768]
// 1327104 partk  int[2*32768]
// 1589248 xsq    float[32768]

// ---- prep: codebook -> bf16 hi/lo split + ||c||^2 ----
__global__ __launch_bounds__(256) void prep_kernel(const float* __restrict__ cb,
        unsigned short* __restrict__ chi, unsigned short* __restrict__ clo,
        float* __restrict__ sq) {
    const int t = threadIdx.x;
    const int row = blockIdx.x * 16 + (t >> 4);
    const int d0 = (t & 15) * 16;
    const float* src = cb + row * 256 + d0;
    short8 h0, h1, l0, l1;
    float s = 0.f;
#pragma unroll
    for (int i = 0; i < 16; ++i) {
        const float v = src[i];
        s += v * v;
        __hip_bfloat16 h = __float2bfloat16(v);
        const float hf = __bfloat162float(h);
        __hip_bfloat16 l = __float2bfloat16(v - hf);
        const short hs = *(short*)&h;
        const short ls = *(short*)&l;
        if (i < 8) { h0[i] = hs; l0[i] = ls; } else { h1[i - 8] = hs; l1[i - 8] = ls; }
    }
    *(short8*)(chi + row * 256 + d0) = h0;
    *(short8*)(chi + row * 256 + d0 + 8) = h1;
    *(short8*)(clo + row * 256 + d0) = l0;
    *(short8*)(clo + row * 256 + d0 + 8) = l1;
#pragma unroll
    for (int off = 1; off < 16; off <<= 1) s += __shfl_xor(s, off);
    if ((t & 15) == 0) sq[row] = s;
}

// ---- argmin via bf16-split MFMA ----
// grid 256 = 128 row-groups x 2 code-halves; block 512 thr = 8 waves.
// wave: M=32 rows (2 A-frags), loops 32 N-tiles of 16 codes (one half).
__global__ __launch_bounds__(512, 2) void argmin_mfma_kernel(
    const float* __restrict__ x,
    const unsigned short* __restrict__ chi, const unsigned short* __restrict__ clo,
    const float* __restrict__ sq,
    float* __restrict__ partv, int* __restrict__ partk, float* __restrict__ xsq_out)
{
    __shared__ unsigned short Bh[2][16][264];   // +8 pad: conflict-optimal b128
    __shared__ unsigned short Bl[2][16][264];
    const int t = threadIdx.x;
    const int lane = t & 63;
    const int w = t >> 6;
    const int m = lane & 15;          // A row / B col / C col class
    const int q = lane >> 4;          // quad
    const int half = blockIdx.x & 1;
    const int rowgrp = blockIdx.x >> 1;
    const int kb = half * 512;
    const int row0 = rowgrp * 256 + w * 32;
    const float* xb = x + (size_t)(row0 >> 10) * (256 * 1024);

    // --- A load: strided global -> bf16 hi/lo frags in regs (one-time) ---
    short8 Ahi[2][8], Alo[2][8];
#pragma unroll
    for (int f = 0; f < 2; ++f) {
        const int hw = (row0 + f * 16 + m) & 1023;
        float xs = 0.f;
#pragma unroll
        for (int ks = 0; ks < 8; ++ks) {
            short8 ah, al;
#pragma unroll
            for (int j = 0; j < 8; ++j) {
                const float v = xb[(size_t)(ks * 32 + q * 8 + j) * 1024 + hw];
                xs += v * v;
                __hip_bfloat16 h = __float2bfloat16(v);
                const float hf = __bfloat162float(h);
                __hip_bfloat16 l = __float2bfloat16(v - hf);
                ah[j] = *(short*)&h;
                al[j] = *(short*)&l;
            }
            Ahi[f][ks] = ah; Alo[f][ks] = al;
        }
        xs += __shfl_xor(xs, 16);
        xs += __shfl_xor(xs, 32);
        if (q == 0) xsq_out[row0 + f * 16 + m] = xs;   // both halves write same value
    }

    // --- B double-buffered staging: tile = 16 codes x 256 d (hi+lo) ---
    const int sc = t >> 5;   // code slot 0..15
    const int sk = t & 31;   // 16B chunk 0..31
    const unsigned short* gh = chi + ((size_t)kb << 8);
    const unsigned short* gl = clo + ((size_t)kb << 8);
    {
        const size_t o = ((size_t)sc << 8) + sk * 8;
        *(short8*)&Bh[0][sc][sk * 8] = *(const short8*)(gh + o);
        *(short8*)&Bl[0][sc][sk * 8] = *(const short8*)(gl + o);
    }

    float bestv[2][4];
    int   bestk[2][4];
#pragma unroll
    for (int f = 0; f < 2; ++f)
#pragma unroll
        for (int r = 0; r < 4; ++r) { bestv[f][r] = 3.4e38f; bestk[f][r] = 0; }

    for (int tile = 0; tile < 32; ++tile) {
        const int buf = tile & 1;
        short8 nh, nl;
        if (tile + 1 < 32) {                       // prefetch next tile (in flight over MFMAs)
            const size_t o = ((size_t)((tile + 1) * 16 + sc) << 8) + sk * 8;
            nh = *(const short8*)(gh + o);
            nl = *(const short8*)(gl + o);
        }
        __syncthreads();                           // buf writes visible
        f32x4 a0 = {0.f, 0.f, 0.f, 0.f}, a1 = {0.f, 0.f, 0.f, 0.f};
#pragma unroll
        for (int ks = 0; ks < 8; ++ks) {
            const short8 bh = *(const short8*)&Bh[buf][m][ks * 32 + q * 8];
            const short8 bl = *(const short8*)&Bl[buf][m][ks * 32 + q * 8];
            a0 = __builtin_amdgcn_mfma_f32_16x16x32_bf16(Ahi[0][ks], bh, a0, 0, 0, 0);
            a1 = __builtin_amdgcn_mfma_f32_16x16x32_bf16(Ahi[1][ks], bh, a1, 0, 0, 0);
            a0 = __builtin_amdgcn_mfma_f32_16x16x32_bf16(Alo[0][ks], bh, a0, 0, 0, 0);
            a1 = __builtin_amdgcn_mfma_f32_16x16x32_bf16(Alo[1][ks], bh, a1, 0, 0, 0);
            a0 = __builtin_amdgcn_mfma_f32_16x16x32_bf16(Ahi[0][ks], bl, a0, 0, 0, 0);
            a1 = __builtin_amdgcn_mfma_f32_16x16x32_bf16(Ahi[1][ks], bl, a1, 0, 0, 0);
        }
        // epilogue: score = ||c||^2 - 2 x.c ; codes ascend with tile -> strict < keeps lowest k
        const int code = kb + tile * 16 + m;
        const float sc2 = sq[code];
#pragma unroll
        for (int f = 0; f < 2; ++f) {
            const f32x4 a = f ? a1 : a0;
#pragma unroll
            for (int r = 0; r < 4; ++r) {
                const float d0 = fmaf(-2.f, a[r], sc2);
                if (d0 < bestv[f][r]) { bestv[f][r] = d0; bestk[f][r] = code; }
            }
        }
        __syncthreads();                           // all waves done reading write-target buf
        if (tile + 1 < 32) {
            *(short8*)&Bh[buf ^ 1][sc][sk * 8] = nh;
            *(short8*)&Bl[buf ^ 1][sc][sk * 8] = nl;
        }
    }

    // --- cross-lane argmin (16 col-classes per row), tie -> lower k ---
#pragma unroll
    for (int f = 0; f < 2; ++f)
#pragma unroll
        for (int r = 0; r < 4; ++r) {
            float v = bestv[f][r];
            int   k = bestk[f][r];
#pragma unroll
            for (int d = 1; d < 16; d <<= 1) {
                const float ov = __shfl_xor(v, d);
                const int   ok = __shfl_xor(k, d);
                if (ov < v || (ov == v && ok < k)) { v = ov; k = ok; }
            }
            if (m == 0) {
                const int grow = row0 + f * 16 + q * 4 + r;
                partv[half * N_VEC + grow] = v;
                partk[half * N_VEC + grow] = k;
            }
        }
}

// ---- fused merge + histogram + loss + gather-scatter ----
__global__ __launch_bounds__(256) void scatter_kernel(
    const float* __restrict__ cb,
    const float* __restrict__ partv, const int* __restrict__ partk,
    const float* __restrict__ xsq, float* __restrict__ out,
    int* __restrict__ counts, float* __restrict__ loss_accum)
{
    __shared__ float Q[64][257];
    __shared__ int codeL[64];
    const int t = threadIdx.x;
    const int n0 = blockIdx.x * 64;
    if (t < 64) {
        const int n = n0 + t;
        const float v0 = partv[n];          const int k0 = partk[n];
        const float v1 = partv[N_VEC + n];  const int k1 = partk[N_VEC + n];
        const int   k = (v1 < v0) ? k1 : k0;   // tie -> half0 (lower codes)
        const float v = (v1 < v0) ? v1 : v0;
        codeL[t] = k;
        atomicAdd(&counts[k], 1);
        float lp = xsq[n] + v;              // ||x-c||^2
#pragma unroll
        for (int off = 32; off > 0; off >>= 1) lp += __shfl_down(lp, off);
        if (t == 0) atomicAdd(loss_accum, lp);
    }
    __syncthreads();
    // stage the 64 selected codebook rows (coalesced 16B reads)
    const int r = t >> 2, qt = t & 3;
    const float* src = cb + (size_t)codeL[r] * 256 + qt * 64;
#pragma unroll
    for (int i = 0; i < 16; ++i) {
        const float4 v = *(const float4*)(src + i * 4);
        Q[r][qt * 64 + i * 4 + 0] = v.x;
        Q[r][qt * 64 + i * 4 + 1] = v.y;
        Q[r][qt * 64 + i * 4 + 2] = v.z;
        Q[r][qt * 64 + i * 4 + 3] = v.w;
    }
    __syncthreads();
    // out = quantized (matches ref x+(q-x) to ~6e-7); coalesced dword stores
    const int hwl = t & 63;
    const int c0 = t >> 6;
    float* dst = out + (size_t)(n0 >> 10) * (256 * 1024) + (n0 & 1023) + hwl;
#pragma unroll 8
    for (int c = c0; c < 256; c += 4)
        dst[(size_t)c * 1024] = Q[hwl][c];
}

__global__ __launch_bounds__(256) void finalize_kernel(
    const int* __restrict__ counts, const float* __restrict__ loss_accum,
    float* __restrict__ out) {
    __shared__ float wsum[4];
    const int t = threadIdx.x;
    float s = 0.f;
#pragma unroll
    for (int mm = 0; mm < 4; ++mm) {
        const float p = (float)counts[t + 256 * mm] * (1.f / 32768.f);
        s += p * logf(p + 1e-10f);
    }
#pragma unroll
    for (int off = 32; off > 0; off >>= 1) s += __shfl_down(s, off);
    if ((t & 63) == 0) wsum[t >> 6] = s;
    __syncthreads();
    if (t == 0) {
        const float total = wsum[0] + wsum[1] + wsum[2] + wsum[3];
        out[OUT_ELEMS]     = loss_accum[0] * (1.25f / 8388608.f);
        out[OUT_ELEMS + 1] = expf(-total);
    }
}

extern "C" void kernel_launch(void* const* d_in, const int* in_sizes, int n_in,
                              void* d_out, int out_size, void* d_ws, size_t ws_size,
                              hipStream_t stream) {
    const float* x  = (const float*)d_in[0];
    const float* cb = (const float*)d_in[1];
    float* out = (float*)d_out;
    char* wsb = (char*)d_ws;
    int*            counts = (int*)(wsb + 0);
    float*          loss   = (float*)(wsb + 4096);
    float*          sq     = (float*)(wsb + 8192);
    unsigned short* chi    = (unsigned short*)(wsb + 16384);
    unsigned short* clo    = (unsigned short*)(wsb + 540672);
    float*          partv  = (float*)(wsb + 1064960);
    int*            partk  = (int*)(wsb + 1327104);
    float*          xsq    = (float*)(wsb + 1589248);

    hipMemsetAsync(d_ws, 0, 8192, stream);
    prep_kernel<<<64, 256, 0, stream>>>(cb, chi, clo, sq);
    argmin_mfma_kernel<<<256, 512, 0, stream>>>(x, chi, clo, sq, partv, partk, xsq);
    scatter_kernel<<<512, 256, 0, stream>>>(cb, partv, partk, xsq, out, counts, loss);
    finalize_kernel<<<1, 256, 0, stream>>>(counts, loss, out);
}